// Round 1
// baseline (400.077 us; speedup 1.0000x reference)
//
#include <hip/hip_runtime.h>

// Fused windowed-signature (depth 2, WIN=5, D=17) + linear head 306->64.
// Layout: x[N=32][C=16][J=25][T=300] f32, W[64][306] f32, b[64] f32,
// out[N][64][J][T] f32.
//
// Math: increments d_1..d_5 (d_1 = p_1, basepoint 0), midpoints
// u_k = (p_{k-1}+p_k)/2. Level1 = p_5, Level2[a][b] = sum_k u_k[a] d_k[b].
// sig = [L1 (17) | L2 (289 row-major)]. z = sig @ W^T + b.

namespace {
constexpr int kN = 32, kC = 16, kJ = 25, kT = 300;
constexpr int kOut = 64, kSig = 306;
constexpr int kTile = 60;          // windows per block (300 = 5*60, exact)
constexpr int kXT = 64;            // kTile + 4 staged x samples
constexpr int kXP = 20;            // padded inner dim (bank spread, 16B-aligned rows)
constexpr int kNTile = 5;
constexpr int kThreads = 512;
}

__global__ __launch_bounds__(kThreads)
void sig_fused_kernel(const float* __restrict__ x, const float* __restrict__ W,
                      const float* __restrict__ bias, float* __restrict__ out) {
  __shared__ float xs[kXT][kXP];           //  5.1 KB
  __shared__ float sigT[kSig][kTile];      // 73.4 KB  sig, transposed [s][w]
  __shared__ float Wall[kSig][kOut];       // 78.3 KB  W, transposed [s][o]

  const int tid  = threadIdx.x;
  const int bid  = blockIdx.x;
  const int tile = bid % kNTile;
  const int j    = (bid / kNTile) % kJ;
  const int n    = bid / (kNTile * kJ);
  const int t0   = tile * kTile;

  // ---- Phase 1a: W -> LDS, transposed to [s][o]. Coalesced float2 reads. ----
  // Flat pair p: W[o][2m..2m+1] lives at float2 index p = o*153 + m.
  for (int p = tid; p < (kSig / 2) * kOut; p += kThreads) {
    float2 w2 = *reinterpret_cast<const float2*>(W + 2 * p);
    int o = p / 153;
    int m = p - o * 153;
    Wall[2 * m    ][o] = w2.x;
    Wall[2 * m + 1][o] = w2.y;
  }

  // ---- Phase 1b: x slab -> LDS (t range [t0-2, t0+61], edge-clamped). ----
  const float* xbase = x + ((n * kC) * kJ + j) * kT;  // + c*kJ*kT + t
  for (int i = tid; i < kXT * kC; i += kThreads) {
    int c  = i >> 6;          // / kXT
    int tt = i & (kXT - 1);
    int tg = t0 - 2 + tt;
    tg = tg < 0 ? 0 : (tg > kT - 1 ? kT - 1 : tg);
    xs[tt][c] = xbase[c * kJ * kT + tg];
  }
  __syncthreads();

  // ---- Phase 2: build signatures into sigT[s][w]. 8 threads per window. ----
  {
    const int w = tid >> 3;   // window 0..63 (only <60 active)
    const int r = tid & 7;
    if (w < kTile) {
      // Increments d[k][c] = x-part of d_{k+1}; statically indexed registers.
      float d[5][16];
      float prev[16];
#pragma unroll
      for (int c = 0; c < 16; ++c) {
        float y0 = xs[w][c];
        d[0][c] = y0;
        prev[c] = y0;
      }
#pragma unroll
      for (int k = 1; k < 5; ++k) {
#pragma unroll
        for (int c = 0; c < 16; ++c) {
          float yk = xs[w + k][c];
          d[k][c] = yk - prev[c];
          prev[c] = yk;
        }
      }
      // Level 1 rows s in {r, r+8, 16 if r==0}: L1[0]=1, L1[1+c]=p5[c].
      {
        sigT[r][w]     = (r == 0) ? 1.0f : xs[w + 4][r - 1];
        sigT[r + 8][w] = xs[w + 4][r + 7];
        if (r == 0) sigT[16][w] = xs[w + 4][15];
      }
      // Level 2 rows a in {r, r+8, 16 if r==0}.
      const int nrows = (r == 0) ? 3 : 2;
      for (int ii = 0; ii < nrows; ++ii) {
        const int a = r + 8 * ii;    // r==0,ii==2 -> a=16
        float u[5];
        if (a == 0) {                // time row: u_k[0] = (tau_{k-1}+tau_k)/2
          u[0] = 0.0f; u[1] = 0.125f; u[2] = 0.375f; u[3] = 0.625f; u[4] = 0.875f;
        } else {
          const int cc = a - 1;      // runtime channel -> read from LDS
          float p0 = xs[w][cc], p1 = xs[w + 1][cc], p2 = xs[w + 2][cc];
          float p3 = xs[w + 3][cc], p4 = xs[w + 4][cc];
          u[0] = 0.5f * p0;
          u[1] = 0.5f * (p0 + p1);
          u[2] = 0.5f * (p1 + p2);
          u[3] = 0.5f * (p2 + p3);
          u[4] = 0.5f * (p3 + p4);
        }
        float* rowp = &sigT[17 + a * 17][w];
        // b == 0: d_k[0] = {0, .25, .25, .25, .25}
        rowp[0] = 0.25f * (u[1] + u[2] + u[3] + u[4]);
#pragma unroll
        for (int b = 1; b < 17; ++b) {
          const int cb = b - 1;
          float acc = u[0] * d[0][cb];
          acc = fmaf(u[1], d[1][cb], acc);
          acc = fmaf(u[2], d[2][cb], acc);
          acc = fmaf(u[3], d[3][cb], acc);
          acc = fmaf(u[4], d[4][cb], acc);
          rowp[b * kTile] = acc;
        }
      }
    }
  }
  __syncthreads();

  // ---- Phase 3: GEMM  out[w][o] = b[o] + sum_s sigT[s][w] * Wall[s][o] ----
  {
    const int og = tid >> 5;          // 0..15 -> o0 = 4*og
    const int wg = tid & 31;          // 0..31, active if wg < 30
    if (wg < 30) {
      const int w0 = 2 * wg;
      const int o0 = 4 * og;
      float acc[2][4];
#pragma unroll
      for (int i = 0; i < 2; ++i)
#pragma unroll
        for (int k = 0; k < 4; ++k) acc[i][k] = 0.0f;

#pragma unroll 6
      for (int s = 0; s < kSig; ++s) {
        float2 sg = *reinterpret_cast<const float2*>(&sigT[s][w0]);
        float4 wv = *reinterpret_cast<const float4*>(&Wall[s][o0]);
        acc[0][0] = fmaf(sg.x, wv.x, acc[0][0]);
        acc[0][1] = fmaf(sg.x, wv.y, acc[0][1]);
        acc[0][2] = fmaf(sg.x, wv.z, acc[0][2]);
        acc[0][3] = fmaf(sg.x, wv.w, acc[0][3]);
        acc[1][0] = fmaf(sg.y, wv.x, acc[1][0]);
        acc[1][1] = fmaf(sg.y, wv.y, acc[1][1]);
        acc[1][2] = fmaf(sg.y, wv.z, acc[1][2]);
        acc[1][3] = fmaf(sg.y, wv.w, acc[1][3]);
      }

      // Store: out[((n*64 + o)*25 + j)*300 + t0 + w], coalesced float2 per o.
#pragma unroll
      for (int oi = 0; oi < 4; ++oi) {
        const int o = o0 + oi;
        const float bo = bias[o];
        float2 res;
        res.x = acc[0][oi] + bo;
        res.y = acc[1][oi] + bo;
        float* dst = out + ((n * kOut + o) * kJ + j) * kT + t0 + w0;
        *reinterpret_cast<float2*>(dst) = res;
      }
    }
  }
}

extern "C" void kernel_launch(void* const* d_in, const int* in_sizes, int n_in,
                              void* d_out, int out_size, void* d_ws, size_t ws_size,
                              hipStream_t stream) {
  const float* x    = (const float*)d_in[0];
  const float* W    = (const float*)d_in[1];
  const float* bias = (const float*)d_in[2];
  float* out        = (float*)d_out;

  dim3 grid(kN * kJ * kNTile);   // 32*25*5 = 4000 blocks
  dim3 block(kThreads);
  hipLaunchKernelGGL(sig_fused_kernel, grid, block, 0, stream, x, W, bias, out);
}

// Round 3
// 356.804 us; speedup vs baseline: 1.1213x; 1.1213x over previous
//
#include <hip/hip_runtime.h>

// Fused windowed-signature (depth 2, WIN=5, D=17) + linear head 306->64.
// x[N=32][C=16][J=25][T=300] f32, W[64][306] f32, b[64] f32 -> out[N][64][J][T] f32.
//
// Math: with basepoint 0, increments d_1..d_5 (d_1 = p_1), midpoints
// u_k = (p_{k-1}+p_k)/2: Level1 = p_5, Level2[a][b] = sum_k u_k[a] d_k[b].
// sig = [L1 (17) | L2 (289)], z = sig @ W^T + b.
//
// R2 structure: 30-window tiles, LDS = sigT[306][30] + xs[34][17] (~38 KB)
// -> 4 blocks/CU (16 waves/CU). W pre-transposed to ws (Wt[306][64]) and read
// via broadcast global_load_dwordx4 (L1/L2-resident). All LDS access patterns
// arranged for <=2-way bank aliasing.

namespace {
constexpr int kN = 32, kC = 16, kJ = 25, kT = 300;
constexpr int kOut = 64, kSig = 306;
constexpr int kTile = 30;          // windows per block (300 = 10*30)
constexpr int kXS = 34;            // staged samples: t in [t0-2, t0+31]
constexpr int kXP = 17;            // odd pad -> stride coprime with 32 banks
constexpr int kNTile = 10;
constexpr int kThreads = 256;
}

// Transpose W[64][306] -> Wt[306][64] (runs every call; ws is re-poisoned).
__global__ __launch_bounds__(256)
void wt_kernel(const float* __restrict__ W, float* __restrict__ Wt) {
  int i = blockIdx.x * 256 + threadIdx.x;
  if (i < kOut * kSig) {
    int o = i / kSig;          // coalesced read over s
    int s = i - o * kSig;
    Wt[s * kOut + o] = W[i];
  }
}

__global__ __launch_bounds__(kThreads, 4)
void sig_fused_kernel(const float* __restrict__ x, const float* __restrict__ Wt,
                      const float* __restrict__ bias, float* __restrict__ out) {
  __shared__ float xs[kXS][kXP];        //  2.3 KB
  __shared__ float sigT[kSig][kTile];   // 35.9 KB   sig, transposed [s][w]

  const int tid  = threadIdx.x;
  const int bid  = blockIdx.x;
  const int tile = bid % kNTile;
  const int j    = (bid / kNTile) % kJ;
  const int n    = bid / (kNTile * kJ);
  const int t0   = tile * kTile;

  // ---- Phase 1: x slab -> LDS, t range [t0-2, t0+31], edge-clamped. ----
  const float* xbase = x + ((n * kC) * kJ + j) * kT;  // + c*kJ*kT + t
  for (int i = tid; i < kXS * kC; i += kThreads) {
    int c  = i / kXS;
    int tt = i - c * kXS;
    int tg = t0 - 2 + tt;
    tg = tg < 0 ? 0 : (tg > kT - 1 ? kT - 1 : tg);
    xs[tt][c] = xbase[c * kJ * kT + tg];
  }
  __syncthreads();

  // ---- Phase 2: build signatures into sigT[s][w]. Lane = w-major so that a
  // wave's lanes write consecutive columns of one row (<=2-way aliasing). ----
  {
    const int w = tid & 31;   // window 0..31 (only <30 active)
    const int r = tid >> 5;   // row group 0..7
    if (w < kTile) {
      // Increments d[k][c]; statically indexed registers only.
      float d[5][16];
      float prev[16];
#pragma unroll
      for (int c = 0; c < 16; ++c) {
        float y0 = xs[w][c];
        d[0][c] = y0;
        prev[c] = y0;
      }
#pragma unroll
      for (int k = 1; k < 5; ++k) {
#pragma unroll
        for (int c = 0; c < 16; ++c) {
          float yk = xs[w + k][c];
          d[k][c] = yk - prev[c];
          prev[c] = yk;
        }
      }
      // Level 1 rows: L1[0]=1 (time endpoint), L1[1+c]=p5[c].
      sigT[r][w]     = (r == 0) ? 1.0f : xs[w + 4][r - 1];
      sigT[r + 8][w] = xs[w + 4][r + 7];
      if (r == 0) sigT[16][w] = xs[w + 4][15];

      // Level 2 rows a in {r, r+8, 16 if r==0}.
      const int nrows = (r == 0) ? 3 : 2;
      for (int ii = 0; ii < nrows; ++ii) {
        const int a = r + 8 * ii;
        float u[5];
        if (a == 0) {  // time row: u_k[0] = (tau_{k-1}+tau_k)/2
          u[0] = 0.0f; u[1] = 0.125f; u[2] = 0.375f; u[3] = 0.625f; u[4] = 0.875f;
        } else {
          const int cc = a - 1;
          float p0 = xs[w][cc], p1 = xs[w + 1][cc], p2 = xs[w + 2][cc];
          float p3 = xs[w + 3][cc], p4 = xs[w + 4][cc];
          u[0] = 0.5f * p0;
          u[1] = 0.5f * (p0 + p1);
          u[2] = 0.5f * (p1 + p2);
          u[3] = 0.5f * (p2 + p3);
          u[4] = 0.5f * (p3 + p4);
        }
        float* rowp = &sigT[17 + a * 17][w];
        // b == 0: d_k[0] = {0, .25, .25, .25, .25}
        rowp[0] = 0.25f * (u[1] + u[2] + u[3] + u[4]);
#pragma unroll
        for (int b = 1; b < 17; ++b) {
          const int cb = b - 1;
          float acc = u[0] * d[0][cb];
          acc = fmaf(u[1], d[1][cb], acc);
          acc = fmaf(u[2], d[2][cb], acc);
          acc = fmaf(u[3], d[3][cb], acc);
          acc = fmaf(u[4], d[4][cb], acc);
          rowp[b * kTile] = acc;
        }
      }
    }
  }
  __syncthreads();

  // ---- Phase 3: out[w][o] = b[o] + sum_s sigT[s][w] * Wt[s][o].
  // og = tid>>4 (16 groups of 4 outputs), wg = tid&15 (15 active pairs of w).
  // sig read: b64, 15 unique even-offset addrs -> conflict-free; 4 og-copies
  // broadcast. W read: global float4, 4 unique addrs/wave, L1-resident. ----
  {
    const int og = tid >> 4;
    const int wg = tid & 15;
    if (wg < 15) {
      const int w0 = 2 * wg;
      const int o0 = 4 * og;
      const float* sp = &sigT[0][w0];
      const float4* wp = reinterpret_cast<const float4*>(Wt) + og;  // + s*16

      float acc[2][4];
#pragma unroll
      for (int i = 0; i < 2; ++i)
#pragma unroll
        for (int k = 0; k < 4; ++k) acc[i][k] = 0.0f;

#pragma unroll 6
      for (int s = 0; s < kSig; ++s) {
        float2 sg = *reinterpret_cast<const float2*>(sp + s * kTile);
        float4 wv = wp[s * (kOut / 4)];
        acc[0][0] = fmaf(sg.x, wv.x, acc[0][0]);
        acc[0][1] = fmaf(sg.x, wv.y, acc[0][1]);
        acc[0][2] = fmaf(sg.x, wv.z, acc[0][2]);
        acc[0][3] = fmaf(sg.x, wv.w, acc[0][3]);
        acc[1][0] = fmaf(sg.y, wv.x, acc[1][0]);
        acc[1][1] = fmaf(sg.y, wv.y, acc[1][1]);
        acc[1][2] = fmaf(sg.y, wv.z, acc[1][2]);
        acc[1][3] = fmaf(sg.y, wv.w, acc[1][3]);
      }

      const float4 bv = *reinterpret_cast<const float4*>(bias + o0);
      const float bb[4] = {bv.x, bv.y, bv.z, bv.w};
#pragma unroll
      for (int oi = 0; oi < 4; ++oi) {
        const int o = o0 + oi;
        float2 res;
        res.x = acc[0][oi] + bb[oi];
        res.y = acc[1][oi] + bb[oi];
        float* dst = out + ((n * kOut + o) * kJ + j) * kT + t0 + w0;
        *reinterpret_cast<float2*>(dst) = res;
      }
    }
  }
}

extern "C" void kernel_launch(void* const* d_in, const int* in_sizes, int n_in,
                              void* d_out, int out_size, void* d_ws, size_t ws_size,
                              hipStream_t stream) {
  const float* x    = (const float*)d_in[0];
  const float* W    = (const float*)d_in[1];
  const float* bias = (const float*)d_in[2];
  float* out        = (float*)d_out;
  float* Wt         = (float*)d_ws;   // 306*64*4 = 78336 B

  {
    dim3 grid((kOut * kSig + 255) / 256);
    hipLaunchKernelGGL(wt_kernel, grid, dim3(256), 0, stream, W, Wt);
  }
  {
    dim3 grid(kN * kJ * kNTile);   // 32*25*10 = 8000 blocks
    hipLaunchKernelGGL(sig_fused_kernel, grid, dim3(kThreads), 0, stream,
                       x, Wt, bias, out);
  }
}

// Round 7
// 151.028 us; speedup vs baseline: 2.6490x; 2.3625x over previous
//
#include <hip/hip_runtime.h>
#include <stdint.h>

// Fused windowed-signature (depth 2, WIN=5, D=17) + linear head 306->64,
// GEMM done on MFMA (bf16 split-precision, 3 products: AhBh+AhBl+AlBh).
//
// x[32][16][25][300] f32, W[64][306] f32, b[64] f32 -> out[32][64][25][300] f32.
// sig (per window, K=306 padded to 320) built in LDS as packed (bf16hi|bf16lo)
// uint32, XOR-swizzled; W packed likewise into d_ws in B-fragment order and
// held B-stationary in 80 VGPRs per wave. mfma_f32_16x16x32_bf16:
//   A: row=lane&15, k=(lane>>4)*8+j ; B: col=lane&15, k=(lane>>4)*8+j
//   D: col=lane&15, row=(lane>>4)*4+reg      [m89-verified layouts]

typedef __attribute__((ext_vector_type(4))) float f32x4;
typedef __attribute__((ext_vector_type(8))) short bf16x8;
typedef __attribute__((ext_vector_type(4))) int i32x4;

namespace {
constexpr int kN = 32, kC = 16, kJ = 25, kT = 300;
constexpr int kOut = 64, kSig = 306, kK = 320;
constexpr int kTile = 30;            // windows per tile (300 = 10*30)
constexpr int kTPS = 10;             // tiles per (n,j) series
constexpr int kTilesTotal = kN * kJ * kTPS;   // 8000
constexpr int kTPB = 4;              // tiles per block -> grid 2000
constexpr int kThreads = 256;
constexpr int kXS = 36, kXP = 20;    // staged x: [t0-2, t0+33], padded row
}

// Swizzled LDS dword offset for sig element (row=window 0..31, s=0..319).
// 16B-slot XOR swizzle: bijective per 8-slot group; row*320 % 32 == 0 so the
// bank-quad is (slot^row)&7 -> 16 lanes span 8 quads = 2-way = free.
__device__ __forceinline__ int lds_off(int row, int s) {
  int slot = s >> 2;
  int sl = (slot & ~7) | ((slot ^ row) & 7);
  return row * 320 + sl * 4 + (s & 3);
}

// Truncate-split pack: hi = v & 0xFFFF0000 (bf16 trunc), lo = v - hi (exact),
// packed = hi_bits | (lo_bits >> 16).  (and, sub, v_perm = 3 ops)
__device__ __forceinline__ uint32_t pack_hl(float v) {
  uint32_t vb = __float_as_uint(v);
  uint32_t hi = vb & 0xFFFF0000u;
  float lo = v - __uint_as_float(hi);
  return __builtin_amdgcn_perm(vb, __float_as_uint(lo), 0x07060302u);
}

// W[64][306] f32 -> WB[(k>>3)*512 + col*8 + (k&7)] packed hi|lo, k padded w/ 0.
__global__ __launch_bounds__(256)
void wt_pack_kernel(const float* __restrict__ W, uint32_t* __restrict__ WB) {
  int i = blockIdx.x * 256 + threadIdx.x;
  if (i < kOut * kK) {
    int col = i / kK;
    int k = i - col * kK;
    float v = (k < kSig) ? W[col * kSig + k] : 0.0f;
    WB[((k >> 3) * kOut + col) * 8 + (k & 7)] = pack_hl(v);
  }
}

union FragU { int i[4]; bf16x8 v; };

__device__ __forceinline__ bf16x8 hi_frag(i32x4 v0, i32x4 v1) {
  FragU f;
  f.i[0] = __builtin_amdgcn_perm((uint32_t)v0.y, (uint32_t)v0.x, 0x07060302u);
  f.i[1] = __builtin_amdgcn_perm((uint32_t)v0.w, (uint32_t)v0.z, 0x07060302u);
  f.i[2] = __builtin_amdgcn_perm((uint32_t)v1.y, (uint32_t)v1.x, 0x07060302u);
  f.i[3] = __builtin_amdgcn_perm((uint32_t)v1.w, (uint32_t)v1.z, 0x07060302u);
  return f.v;
}
__device__ __forceinline__ bf16x8 lo_frag(i32x4 v0, i32x4 v1) {
  FragU f;
  f.i[0] = __builtin_amdgcn_perm((uint32_t)v0.y, (uint32_t)v0.x, 0x05040100u);
  f.i[1] = __builtin_amdgcn_perm((uint32_t)v0.w, (uint32_t)v0.z, 0x05040100u);
  f.i[2] = __builtin_amdgcn_perm((uint32_t)v1.y, (uint32_t)v1.x, 0x05040100u);
  f.i[3] = __builtin_amdgcn_perm((uint32_t)v1.w, (uint32_t)v1.z, 0x05040100u);
  return f.v;
}

__global__ __launch_bounds__(kThreads, 3)
void sig_mfma_kernel(const float* __restrict__ x, const uint32_t* __restrict__ WB,
                     const float* __restrict__ bias, float* __restrict__ out) {
  __shared__ uint32_t sig32[32 * 320];   // 40960 B, packed hi|lo, swizzled
  __shared__ float xs[kXS][kXP];         //  2880 B

  const int tid = threadIdx.x;
  const int lane = tid & 63;
  const int wid = tid >> 6;        // wave id = N-tile (16 output cols)
  const int l15 = lane & 15;
  const int l4 = lane >> 4;

  // ---- B-stationary preload: this wave's 16 cols, all K, hi+lo (80 VGPR) ----
  const int col = wid * 16 + l15;
  bf16x8 Bh[10], Bl[10];
#pragma unroll
  for (int st = 0; st < 10; ++st) {
    int kt = st * 4 + l4;
    const i32x4* p = reinterpret_cast<const i32x4*>(WB + ((size_t)(kt * kOut + col)) * 8);
    i32x4 v0 = p[0], v1 = p[1];
    Bh[st] = hi_frag(v0, v1);
    Bl[st] = lo_frag(v0, v1);
  }
  const float myb = bias[col];

  // ---- One-time zero: A rows 30,31 (full) + K-pad s in [306,320) rows 0..29.
  for (int i = tid; i < 640; i += kThreads) sig32[30 * 320 + i] = 0;
  for (int i = tid; i < 30 * 14; i += kThreads) {
    int row = i / 14, s = 306 + i % 14;
    sig32[lds_off(row, s)] = 0;
  }

  for (int it = 0; it < kTPB; ++it) {
    const int g = blockIdx.x * kTPB + it;
    const int series = g / kTPS;
    const int t0 = (g - series * kTPS) * kTile;
    const int n = series / kJ;
    const int j = series - n * kJ;

    __syncthreads();  // prev tile's LDS readers done before restage

    // ---- Phase 1: stage x window slab (edge-clamped) ----
    const float* xbase = x + ((size_t)(n * kC) * kJ + j) * kT;
    for (int i = tid; i < kXS * kC; i += kThreads) {
      int c = i / kXS, tt = i - c * kXS;
      int tg = t0 - 2 + tt;
      tg = tg < 0 ? 0 : (tg > kT - 1 ? kT - 1 : tg);
      xs[tt][c] = xbase[c * kJ * kT + tg];
    }
    __syncthreads();

    // ---- Phase 2: build packed sig rows. 16 threads/window, 2 passes. ----
#pragma unroll
    for (int pass = 0; pass < 2; ++pass) {
      const int w = pass * 16 + (tid >> 4);
      if (w < kTile) {
        const int sub = tid & 15;
        const int hb = sub & 1;        // channel half (8 channels)
        const int r = sub >> 1;        // a-row group

        // Level 1 (s = 0..16): endpoint (1, p5). One write per thread.
        sig32[lds_off(w, sub)] = pack_hl(sub == 0 ? 1.0f : xs[w + 4][sub - 1]);
        if (sub == 0) sig32[lds_off(w, 16)] = pack_hl(xs[w + 4][15]);

        // d[k][c] for this half: d1 = q1 (basepoint 0), dk = qk - q(k-1).
        float d[5][8];
        {
          float4 a0 = *reinterpret_cast<const float4*>(&xs[w][hb * 8]);
          float4 a1 = *reinterpret_cast<const float4*>(&xs[w][hb * 8 + 4]);
          float pv[8] = {a0.x, a0.y, a0.z, a0.w, a1.x, a1.y, a1.z, a1.w};
#pragma unroll
          for (int c = 0; c < 8; ++c) d[0][c] = pv[c];
#pragma unroll
          for (int k = 1; k < 5; ++k) {
            float4 b0 = *reinterpret_cast<const float4*>(&xs[w + k][hb * 8]);
            float4 b1 = *reinterpret_cast<const float4*>(&xs[w + k][hb * 8 + 4]);
            float cv[8] = {b0.x, b0.y, b0.z, b0.w, b1.x, b1.y, b1.z, b1.w};
#pragma unroll
            for (int c = 0; c < 8; ++c) { d[k][c] = cv[c] - pv[c]; pv[c] = cv[c]; }
          }
        }

        const int nrows = (r == 0) ? 3 : 2;
        for (int ii = 0; ii < nrows; ++ii) {
          const int a = r + 8 * ii;    // r==0,ii==2 -> a=16
          float u[5];
          if (a == 0) {
            u[0] = 0.0f; u[1] = 0.125f; u[2] = 0.375f; u[3] = 0.625f; u[4] = 0.875f;
          } else {
            const int ca = a - 1;
            float p0 = xs[w][ca], p1 = xs[w + 1][ca], p2 = xs[w + 2][ca];
            float p3 = xs[w + 3][ca], p4 = xs[w + 4][ca];
            u[0] = 0.5f * p0;
            u[1] = 0.5f * (p0 + p1);
            u[2] = 0.5f * (p1 + p2);
            u[3] = 0.5f * (p2 + p3);
            u[4] = 0.5f * (p3 + p4);
          }
          const int sbase = 17 + a * 17;
          if (hb == 0) {  // b==0 column: d_k[0] = {0,.25,.25,.25,.25}
            sig32[lds_off(w, sbase)] = pack_hl(0.25f * (u[1] + u[2] + u[3] + u[4]));
          }
#pragma unroll
          for (int bj = 0; bj < 8; ++bj) {
            float val = u[0] * d[0][bj];
            val = fmaf(u[1], d[1][bj], val);
            val = fmaf(u[2], d[2][bj], val);
            val = fmaf(u[3], d[3][bj], val);
            val = fmaf(u[4], d[4][bj], val);
            sig32[lds_off(w, sbase + 1 + hb * 8 + bj)] = pack_hl(val);
          }
        }
      }
    }
    __syncthreads();

    // ---- Phase 3: MFMA.  D[w][o] tiles: 2 M-tiles x this wave's N-tile. ----
    f32x4 acc0 = {0.f, 0.f, 0.f, 0.f};
    f32x4 acc1 = {0.f, 0.f, 0.f, 0.f};
#pragma unroll
    for (int st = 0; st < 10; ++st) {
      const int slotb = st * 8 + (l4 << 1);
      {  // mt = 0: rows = l15
        const int row = l15;
        const int sl0 = (slotb & ~7) | ((slotb ^ row) & 7);
        const int sl1 = ((slotb + 1) & ~7) | (((slotb + 1) ^ row) & 7);
        i32x4 v0 = *reinterpret_cast<const i32x4*>(&sig32[row * 320 + sl0 * 4]);
        i32x4 v1 = *reinterpret_cast<const i32x4*>(&sig32[row * 320 + sl1 * 4]);
        bf16x8 Ah = hi_frag(v0, v1), Al = lo_frag(v0, v1);
        acc0 = __builtin_amdgcn_mfma_f32_16x16x32_bf16(Ah, Bh[st], acc0, 0, 0, 0);
        acc0 = __builtin_amdgcn_mfma_f32_16x16x32_bf16(Ah, Bl[st], acc0, 0, 0, 0);
        acc0 = __builtin_amdgcn_mfma_f32_16x16x32_bf16(Al, Bh[st], acc0, 0, 0, 0);
      }
      {  // mt = 1: rows = 16 + l15
        const int row = 16 + l15;
        const int sl0 = (slotb & ~7) | ((slotb ^ row) & 7);
        const int sl1 = ((slotb + 1) & ~7) | (((slotb + 1) ^ row) & 7);
        i32x4 v0 = *reinterpret_cast<const i32x4*>(&sig32[row * 320 + sl0 * 4]);
        i32x4 v1 = *reinterpret_cast<const i32x4*>(&sig32[row * 320 + sl1 * 4]);
        bf16x8 Ah = hi_frag(v0, v1), Al = lo_frag(v0, v1);
        acc1 = __builtin_amdgcn_mfma_f32_16x16x32_bf16(Ah, Bh[st], acc1, 0, 0, 0);
        acc1 = __builtin_amdgcn_mfma_f32_16x16x32_bf16(Ah, Bl[st], acc1, 0, 0, 0);
        acc1 = __builtin_amdgcn_mfma_f32_16x16x32_bf16(Al, Bh[st], acc1, 0, 0, 0);
      }
    }

    // ---- Store: lane holds rows (l4*4 + reg) of its mt, col = o. t = t0+w. ----
    const size_t obase = ((size_t)(n * kOut + col) * kJ + j) * kT;
    const int tb0 = t0 + (l4 << 2);
    {
      float2 s01 = {acc0.x + myb, acc0.y + myb};
      float2 s23 = {acc0.z + myb, acc0.w + myb};
      *reinterpret_cast<float2*>(&out[obase + tb0]) = s01;
      *reinterpret_cast<float2*>(&out[obase + tb0 + 2]) = s23;
    }
    {
      const int tb1 = tb0 + 16;
      float2 s01 = {acc1.x + myb, acc1.y + myb};
      *reinterpret_cast<float2*>(&out[obase + tb1]) = s01;
      if (l4 != 3) {  // rows 30,31 (w >= kTile) masked out
        float2 s23 = {acc1.z + myb, acc1.w + myb};
        *reinterpret_cast<float2*>(&out[obase + tb1 + 2]) = s23;
      }
    }
  }
}

extern "C" void kernel_launch(void* const* d_in, const int* in_sizes, int n_in,
                              void* d_out, int out_size, void* d_ws, size_t ws_size,
                              hipStream_t stream) {
  const float* x = (const float*)d_in[0];
  const float* W = (const float*)d_in[1];
  const float* bias = (const float*)d_in[2];
  float* out = (float*)d_out;
  uint32_t* WB = (uint32_t*)d_ws;   // 320*64*4 = 81920 B

  {
    dim3 grid((kOut * kK + 255) / 256);   // 80 blocks
    hipLaunchKernelGGL(wt_pack_kernel, grid, dim3(256), 0, stream, W, WB);
  }
  {
    dim3 grid(kTilesTotal / kTPB);        // 2000 blocks
    hipLaunchKernelGGL(sig_mfma_kernel, grid, dim3(kThreads), 0, stream,
                       x, WB, bias, out);
  }
}